// Round 7
// baseline (1714.308 us; speedup 1.0000x reference)
//
#include <hip/hip_runtime.h>
#include <float.h>

// Volume geometry: (B=2, C=1, D=192, H=192, W=192) fp32 in/out.
// Erosion chain + skel stored fp16 (min/max are selections -> one initial
// rounding, no accumulation; skel rounds once per DOUBLE step now).
// Each double_k executes TWO skeleton steps: reads A_{j-1}, A_j, S; computes
// T=erode(A_j)=A_{j+1} in-register (5-row / x+-2 halo), dilates both A_j and T,
// updates S twice, writes T, U=erode(T)=A_{j+2}, S.
#define Dn 192
#define Hn 192
#define Wn 192
#define PLANE (Hn * Wn)            // 36864 elems
#define W4n 48                     // 4-elem groups per row
#define TOTAL_ELEMS 14155776       // 2*192^3
#define TOTAL_T (TOTAL_ELEMS / 4)  // 3538944 4-elem groups
#define ZPT 8                      // z per thread
#define ZC (Dn / ZPT)              // 24 z-chunks
#define NBLK_F (TOTAL_T / ZPT / 256)  // 1728 blocks (fused/double)
#define NBLK_E (TOTAL_T / 256)        // 13824 blocks (standalone erode)

typedef _Float16 half4 __attribute__((ext_vector_type(4)));
typedef _Float16 half2t __attribute__((ext_vector_type(2)));

__device__ __forceinline__ float4 f4min(float4 a, float4 b) {
    return make_float4(fminf(a.x, b.x), fminf(a.y, b.y), fminf(a.z, b.z), fminf(a.w, b.w));
}
__device__ __forceinline__ float4 f4max(float4 a, float4 b) {
    return make_float4(fmaxf(a.x, b.x), fmaxf(a.y, b.y), fmaxf(a.z, b.z), fmaxf(a.w, b.w));
}
__device__ __forceinline__ float4 f4relu(float4 a) {
    return make_float4(fmaxf(a.x, 0.f), fmaxf(a.y, 0.f), fmaxf(a.z, 0.f), fmaxf(a.w, 0.f));
}
__device__ __forceinline__ float4 h4tof4(half4 h) {
    return make_float4((float)h.x, (float)h.y, (float)h.z, (float)h.w);
}
__device__ __forceinline__ half4 f4toh4(float4 f) {
    half4 h; h.x = (_Float16)f.x; h.y = (_Float16)f.y;
    h.z = (_Float16)f.z; h.w = (_Float16)f.w; return h;
}
__device__ __forceinline__ _Float16 hmin(_Float16 a, _Float16 b) { return a < b ? a : b; }
__device__ __forceinline__ _Float16 hmax(_Float16 a, _Float16 b) { return a > b ? a : b; }
__device__ __forceinline__ half4 h4min(half4 a, half4 b) {
    half4 o; o.x=hmin(a.x,b.x); o.y=hmin(a.y,b.y); o.z=hmin(a.z,b.z); o.w=hmin(a.w,b.w); return o;
}
__device__ __forceinline__ half4 h4max(half4 a, half4 b) {
    half4 o; o.x=hmax(a.x,b.x); o.y=hmax(a.y,b.y); o.z=hmax(a.z,b.z); o.w=hmax(a.w,b.w); return o;
}
__device__ __forceinline__ _Float16 shfl_up_h(_Float16 v) { return (_Float16)__shfl_up((float)v, 1); }
__device__ __forceinline__ _Float16 shfl_dn_h(_Float16 v) { return (_Float16)__shfl_down((float)v, 1); }
__device__ __forceinline__ float4 skel_upd(float4 s, float4 d) {
    s.x += fmaxf(d.x - s.x * d.x, 0.f);
    s.y += fmaxf(d.y - s.y * d.y, 0.f);
    s.z += fmaxf(d.z - s.z * d.z, 0.f);
    s.w += fmaxf(d.w - s.w * d.w, 0.f);
    return s;
}

// XCD-aware swizzle: contiguous slab per XCD so stencil reuse hits its L2.
template <int CHUNK>
__device__ __forceinline__ int swizzle(int bid) {
    return (bid & 7) * CHUNK + (bid >> 3);
}

// ---------- double-step kernel machinery ----------

struct Off { int o[5]; };  // y-2..y+2 row offsets, neutral-clamped at bounds
// Raw plane: 5 rows (half4) + patch cols for edge lanes:
//  lane0 (w4>0):  pp[k] = {x-2, x-1}  (.x=outer, .y=inner)
//  lane63(w4<47): pp[k] = {x+4, x+5}  (.x=inner, .y=outer)
struct Raw5 { half4 r[5]; half2t pp[5]; };

__device__ __forceinline__ void load_raw5(const _Float16* __restrict__ A, int pb,
                                          const Off& off, int w4, int lane, Raw5& o) {
    const _Float16* p = A + pb;
#pragma unroll
    for (int k = 0; k < 5; ++k) o.r[k] = *(const half4*)(p + off.o[k]);
    bool eL = (lane == 0 && w4 > 0), eR = (lane == 63 && w4 < 47);
    if (eL || eR) {
        const _Float16* q = p + (eL ? -2 : 4);
#pragma unroll
        for (int k = 0; k < 5; ++k) o.pp[k] = *(const half2t*)(q + off.o[k]);
    }
}

// From raw planes Rm (z-1), Rc (z), Rp (z+1): compute T=erode(C) plane z's
// summaries for the subsequent dilate/erode of T, plus the 3x3 box-max of C
// plane z. All fp16 (exact selections).
//   mxT = 3x3 box-max of T; stT = in-plane star-min of T; crT = center T row;
//   mxC = 3x3 box-max of C.
__device__ __forceinline__ void make_T(const Raw5& Rm, const Raw5& Rc, const Raw5& Rp,
                                       int y, int w4, int lane,
                                       half4& mxT, half4& stT, half4& crT, half4& mxC) {
    bool eL = (lane == 0 && w4 > 0), eR = (lane == 63 && w4 < 47);
    half4 Trow[3]; _Float16 Tp[3];
#pragma unroll
    for (int k = 1; k <= 3; ++k) {
        half4 v = Rc.r[k];
        _Float16 l = shfl_up_h(v.w);
        _Float16 rr = shfl_dn_h(v.x);
        if (eL) l = Rc.pp[k].y;
        if (eR) rr = Rc.pp[k].x;
        if (w4 == 0)  l = v.x;    // neutral pad (already in reduction)
        if (w4 == 47) rr = v.w;
        half4 vL = {l, v.x, v.y, v.z};
        half4 vR = {v.y, v.z, v.w, rr};
        half4 t = h4min(h4min(vL, vR), v);
        t = h4min(t, h4min(Rc.r[k - 1], Rc.r[k + 1]));
        t = h4min(t, h4min(Rm.r[k], Rp.r[k]));
        Trow[k - 1] = t;
        // T at the patch (inner) column — only meaningful for edge lanes.
        _Float16 inner = eL ? Rc.pp[k].y : Rc.pp[k].x;
        _Float16 outer = eL ? Rc.pp[k].x : Rc.pp[k].y;
        _Float16 own   = eL ? v.x : v.w;
        _Float16 h = hmin(hmin(inner, outer), own);
        h = hmin(h, hmin(eL ? Rc.pp[k - 1].y : Rc.pp[k - 1].x,
                         eL ? Rc.pp[k + 1].y : Rc.pp[k + 1].x));
        h = hmin(h, hmin(eL ? Rm.pp[k].y : Rm.pp[k].x,
                         eL ? Rp.pp[k].y : Rp.pp[k].x));
        Tp[k - 1] = h;
    }
    // y-boundary: padded Trow formula is NOT neutral for the later max — must
    // substitute the valid neighbor row explicitly.
    if (y == 0)      { Trow[0] = Trow[1]; Tp[0] = Tp[1]; }
    if (y == Hn - 1) { Trow[2] = Trow[1]; Tp[2] = Tp[1]; }

    half4 vM = h4max(Trow[0], h4max(Trow[1], Trow[2]));
    _Float16 lM = shfl_up_h(vM.w), rM = shfl_dn_h(vM.x);
    _Float16 pmT = hmax(Tp[0], hmax(Tp[1], Tp[2]));
    if (eL) lM = pmT;
    if (eR) rM = pmT;
    if (w4 == 0)  lM = vM.x;
    if (w4 == 47) rM = vM.w;
    half4 ML = {lM, vM.x, vM.y, vM.z};
    half4 MR = {vM.y, vM.z, vM.w, rM};
    mxT = h4max(h4max(ML, MR), vM);

    half4 tc = Trow[1];
    _Float16 lC = shfl_up_h(tc.w), rC = shfl_dn_h(tc.x);
    if (eL) lC = Tp[1];
    if (eR) rC = Tp[1];
    if (w4 == 0)  lC = tc.x;
    if (w4 == 47) rC = tc.w;
    half4 CL = {lC, tc.x, tc.y, tc.z};
    half4 CR = {tc.y, tc.z, tc.w, rC};
    stT = h4min(h4min(h4min(CL, CR), tc), h4min(Trow[0], Trow[2]));
    crT = tc;

    half4 vC = h4max(Rc.r[1], h4max(Rc.r[2], Rc.r[3]));
    _Float16 lE = shfl_up_h(vC.w), rE = shfl_dn_h(vC.x);
    _Float16 i1 = eL ? Rc.pp[1].y : Rc.pp[1].x;
    _Float16 i2 = eL ? Rc.pp[2].y : Rc.pp[2].x;
    _Float16 i3 = eL ? Rc.pp[3].y : Rc.pp[3].x;
    _Float16 pmC = hmax(i1, hmax(i2, i3));
    if (eL) lE = pmC;
    if (eR) rE = pmC;
    if (w4 == 0)  lE = vC.x;
    if (w4 == 47) rE = vC.w;
    half4 EL = {lE, vC.x, vC.y, vC.z};
    half4 ER = {vC.y, vC.z, vC.w, rE};
    mxC = h4max(h4max(EL, ER), vC);
}

// Double step kernel: steps j (=2t+1) and j+1. P=A_{j-1} (fp32 img if FIRSTE),
// C=A_j. Writes T=A_{j+1} (may alias P in-place: P read only at own base),
// U=A_{j+2}, S (updated twice, fp32 in-register between the two updates).
template <bool FIRSTE>
__global__ __launch_bounds__(256, 2) void double_k(const void* P_,
                                                   const _Float16* __restrict__ C,
                                                   _Float16* S,
                                                   _Float16* T,
                                                   _Float16* __restrict__ U) {
    const float* Pf = (const float*)P_;
    const _Float16* Ph = (const _Float16*)P_;
    int t = swizzle<NBLK_F / 8>(blockIdx.x) * 256 + threadIdx.x;
    int lane = threadIdx.x & 63;
    int w4 = t % W4n;
    int r  = t / W4n;
    int y  = r % Hn;
    int r2 = r / Hn;
    int zc = r2 % ZC;   // wave-uniform
    int b  = r2 / ZC;
    int z0 = zc * ZPT;
    int base0 = ((b * Dn + z0) * Hn + y) * Wn + w4 * 4;

    Off off;
    off.o[2] = 0;
    off.o[1] = (y > 0)      ? -Wn     : 0;
    off.o[0] = (y > 1)      ? -2 * Wn : off.o[1];
    off.o[3] = (y < Hn - 1) ?  Wn     : 0;
    off.o[4] = (y < Hn - 2) ?  2 * Wn : off.o[3];

    Raw5 R[4];
    half4 mxTm, mxTc, crTm, crTc, stTc, mxCm, mxCc;
    float4 ePf; half4 ePh, sPh;

    // Prologue: planes z0-2..z0+2 (z0-2/-1 transient), P/S at z0.
    if (z0 > 0) {
        Raw5 Rm2, Rm1;
        load_raw5(C, base0 - 2 * PLANE, off, w4, lane, Rm2);
        load_raw5(C, base0 - PLANE,     off, w4, lane, Rm1);
        load_raw5(C, base0,             off, w4, lane, R[0]);
        load_raw5(C, base0 + PLANE,     off, w4, lane, R[1]);
        if (FIRSTE) ePf = *(const float4*)(Pf + base0);
        else        ePh = *(const half4*)(Ph + base0);
        if (!FIRSTE) sPh = *(const half4*)(S + base0);
        half4 dum;
        make_T(Rm2, Rm1, R[0], y, w4, lane, mxTm, dum, crTm, mxCm);   // T(z0-1)
        make_T(Rm1, R[0], R[1], y, w4, lane, mxTc, stTc, crTc, mxCc); // T(z0)
        load_raw5(C, base0 + 2 * PLANE, off, w4, lane, R[2]);
    } else {
        load_raw5(C, base0,             off, w4, lane, R[0]);
        load_raw5(C, base0 + PLANE,     off, w4, lane, R[1]);
        load_raw5(C, base0 + 2 * PLANE, off, w4, lane, R[2]);
        if (FIRSTE) ePf = *(const float4*)(Pf + base0);
        else        ePh = *(const half4*)(Ph + base0);
        if (!FIRSTE) sPh = *(const half4*)(S + base0);
        make_T(R[0], R[0], R[1], y, w4, lane, mxTc, stTc, crTc, mxCc); // T(0), z-pad
        mxTm = mxTc; crTm = crTc; mxCm = mxCc;
    }

    int pb = base0;
#pragma unroll
    for (int i = 0; i < ZPT; ++i) {
        int z = z0 + i;
        // 1) issue raw loads for plane z+3 (consumed next iter)
        if (i + 1 < ZPT && z + 3 < Dn)
            load_raw5(C, pb + 3 * PLANE, off, w4, lane, R[(i + 3) & 3]);
        // 2) prefetch P/S for z+1
        float4 eNf = ePf; half4 eNh = ePh, sNh = sPh;
        if (i + 1 < ZPT) {
            if (FIRSTE) eNf = *(const float4*)(Pf + pb + PLANE);
            else        eNh = *(const half4*)(Ph + pb + PLANE);
            if (!FIRSTE) sNh = *(const half4*)(S + pb + PLANE);
        }
        // 3) T(z+1), mxC(z+1)
        half4 mxT2, stT2, crT2, mxC2;
        if (z + 1 < Dn) {
            const Raw5& Rm = R[i & 3];
            const Raw5& Rc = R[(i + 1) & 3];
            const Raw5& Rp = R[((z + 2 < Dn) ? (i + 2) : (i + 1)) & 3];
            make_T(Rm, Rc, Rp, y, w4, lane, mxT2, stT2, crT2, mxC2);
        } else {  // z+1 == Dn: neutral z-pad
            mxT2 = mxTc; stT2 = stTc; crT2 = crTc; mxC2 = mxCc;
        }
        // 4) step j: delta1 = relu(P - dilate(C))
        float4 dil1 = h4tof4(h4max(mxCm, h4max(mxCc, mxC2)));
        float4 e1 = FIRSTE ? ePf : h4tof4(ePh);
        float4 d1 = f4relu(make_float4(e1.x - dil1.x, e1.y - dil1.y,
                                       e1.z - dil1.z, e1.w - dil1.w));
        float4 s;
        if (FIRSTE) s = d1;                       // skel starts at 0
        else        s = skel_upd(h4tof4(sPh), d1);
        // 5) step j+1: delta2 = relu(C - dilate(T)), E=C(z) free in registers
        float4 dil2 = h4tof4(h4max(mxTm, h4max(mxTc, mxT2)));
        float4 e2 = h4tof4(R[i & 3].r[2]);
        float4 d2 = f4relu(make_float4(e2.x - dil2.x, e2.y - dil2.y,
                                       e2.z - dil2.z, e2.w - dil2.w));
        s = skel_upd(s, d2);
        // 6) stores
        *(half4*)(S + pb) = f4toh4(s);
        *(half4*)(T + pb) = crTc;                          // A_{j+1}(z)
        *(half4*)(U + pb) = h4min(stTc, h4min(crTm, crT2)); // A_{j+2}(z)
        // 7) rotate
        mxCm = mxCc; mxCc = mxC2; mxTm = mxTc; mxTc = mxT2;
        crTm = crTc; crTc = crT2; stTc = stT2;
        ePf = eNf; ePh = eNh; sPh = sNh;
        pb += PLANE;
    }
}

// ---------- single-step machinery (known-good from R6) ----------

__device__ __forceinline__ float4 hmax3n(float4 v, float nl, float nr, int w4) {
    float l = (w4 > 0)  ? nl : v.x;
    float r = (w4 < 47) ? nr : v.w;
    return make_float4(fmaxf(fmaxf(l, v.x), v.y), fmaxf(fmaxf(v.x, v.y), v.z),
                       fmaxf(fmaxf(v.y, v.z), v.w), fmaxf(fmaxf(v.z, v.w), r));
}
__device__ __forceinline__ float4 hmin3n(float4 v, float nl, float nr, int w4) {
    float l = (w4 > 0)  ? nl : v.x;
    float r = (w4 < 47) ? nr : v.w;
    return make_float4(fminf(fminf(l, v.x), v.y), fminf(fminf(v.x, v.y), v.z),
                       fminf(fminf(v.y, v.z), v.w), fminf(fminf(v.z, v.w), r));
}

struct Raw { half4 u, c, d; _Float16 pu, pc, pd; };

__device__ __forceinline__ void load_raw(const _Float16* __restrict__ A, int pb,
                                         bool hasU, bool hasD, int w4, int lane,
                                         Raw& r) {
    const _Float16* p = A + pb;
    r.c = *(const half4*)p;
    half4 u = r.c, d = r.c;
    if (hasU) u = *(const half4*)(p - Wn);
    if (hasD) d = *(const half4*)(p + Wn);
    r.u = u; r.d = d;
    r.pu = r.pc = r.pd = (_Float16)0.f;
    int o = (lane == 0) ? -1 : 4;
    if ((lane == 0 && w4 > 0) || (lane == 63 && w4 < 47)) {
        _Float16 pc = p[o];
        _Float16 pu = pc, pd = pc;
        if (hasU) pu = p[o - Wn];
        if (hasD) pd = p[o + Wn];
        r.pc = pc; r.pu = pu; r.pd = pd;
    }
}

__device__ __forceinline__ void summarize(const Raw& r, int w4, int lane,
                                          float4& mx, float4& st, float4& cr) {
    float4 c = h4tof4(r.c), u = h4tof4(r.u), d = h4tof4(r.d);
    float4 mv = f4max(c, f4max(u, d));
    float mvl = __shfl_up(mv.w, 1);
    float mvr = __shfl_down(mv.x, 1);
    float cl  = __shfl_up(c.w, 1);
    float crr = __shfl_down(c.x, 1);
    float puf = (float)r.pu, pcf = (float)r.pc, pdf = (float)r.pd;
    float pm = fmaxf(pcf, fmaxf(puf, pdf));
    if (lane == 0 && w4 > 0)   { mvl = pm; cl = pcf; }
    if (lane == 63 && w4 < 47) { mvr = pm; crr = pcf; }
    mx = hmax3n(mv, mvl, mvr, w4);
    st = f4min(hmin3n(c, cl, crr, w4), f4min(u, d));
    cr = c;
}

// Standalone erode: A_1 = erode(img). fp32 in, fp16 out. 7-star min.
__global__ __launch_bounds__(256) void erode_k(const float* __restrict__ in,
                                               _Float16* __restrict__ out) {
    int t = swizzle<NBLK_E / 8>(blockIdx.x) * 256 + threadIdx.x;
    int lane = threadIdx.x & 63;
    int w4 = t % W4n;
    int r  = t / W4n;
    int y  = r % Hn;
    int r2 = r / Hn;
    int z  = r2 % Dn;
    int b  = r2 / Dn;
    int base = ((b * Dn + z) * Hn + y) * Wn + w4 * 4;

    const float* p = in + base;
    float4 c = *(const float4*)p;
    float nl = __shfl_up(c.w, 1), nr = __shfl_down(c.x, 1);
    if (lane == 0 && w4 > 0)   nl = p[-1];
    if (lane == 63 && w4 < 47) nr = p[4];
    float4 acc = hmin3n(c, nl, nr, w4);
    if (z > 0)      acc = f4min(acc, *(const float4*)(p - PLANE));
    if (z < Dn - 1) acc = f4min(acc, *(const float4*)(p + PLANE));
    if (y > 0)      acc = f4min(acc, *(const float4*)(p - Wn));
    if (y < Hn - 1) acc = f4min(acc, *(const float4*)(p + Wn));
    *(half4*)(out + base) = f4toh4(acc);
}

// Final single step (j=41): delta = relu(E - dilate(A)); skel update; writes
// fp32 to d_out. A=A_41, E=A_40, Sin fp16.
__global__ __launch_bounds__(256, 4) void final_k(const _Float16* __restrict__ A,
                                                  const _Float16* __restrict__ E,
                                                  const _Float16* __restrict__ Sin,
                                                  float* __restrict__ Sout) {
    int t = swizzle<NBLK_F / 8>(blockIdx.x) * 256 + threadIdx.x;
    int lane = threadIdx.x & 63;
    int w4 = t % W4n;
    int r  = t / W4n;
    int y  = r % Hn;
    int r2 = r / Hn;
    int zc = r2 % ZC;
    int b  = r2 / ZC;
    int z0 = zc * ZPT;
    bool hasU = (y > 0), hasD = (y < Hn - 1);
    int base0 = ((b * Dn + z0) * Hn + y) * Wn + w4 * 4;

    float4 mx0, mx1, mx2, st0, st1, st2, cr0, cr1, cr2;
    Raw bufA, bufB, rP;

    if (z0 > 0) load_raw(A, base0 - PLANE, hasU, hasD, w4, lane, rP);
    load_raw(A, base0,         hasU, hasD, w4, lane, bufB);
    load_raw(A, base0 + PLANE, hasU, hasD, w4, lane, bufA);
    half4 ePh = *(const half4*)(E + base0);
    half4 sPh = *(const half4*)(Sin + base0);

    if (z0 > 0) summarize(rP, w4, lane, mx0, st0, cr0);
    summarize(bufB, w4, lane, mx1, st1, cr1);
    if (z0 == 0) { mx0 = mx1; st0 = st1; cr0 = cr1; }

    int pb = base0;
#pragma unroll
    for (int i = 0; i < ZPT; ++i) {
        Raw& cur = (i & 1) ? bufB : bufA;
        Raw& nxt = (i & 1) ? bufA : bufB;
        if (i + 1 < ZPT && z0 + i + 2 < Dn)
            load_raw(A, pb + 2 * PLANE, hasU, hasD, w4, lane, nxt);
        half4 eNh = ePh, sNh = sPh;
        if (i + 1 < ZPT) {
            eNh = *(const half4*)(E + pb + PLANE);
            sNh = *(const half4*)(Sin + pb + PLANE);
        }
        if (z0 + i + 1 < Dn) summarize(cur, w4, lane, mx2, st2, cr2);
        else { mx2 = mx1; st2 = st1; cr2 = cr1; }
        float4 dil = f4max(mx1, f4max(mx0, mx2));
        float4 e = h4tof4(ePh);
        float4 delta = f4relu(make_float4(e.x - dil.x, e.y - dil.y,
                                          e.z - dil.z, e.w - dil.w));
        float4 s = skel_upd(h4tof4(sPh), delta);
        *(float4*)(Sout + pb) = s;
        mx0 = mx1; st0 = st1; cr0 = cr1;
        mx1 = mx2; st1 = st2; cr1 = cr2;
        ePh = eNh; sPh = sNh;
        pb += PLANE;
    }
}

extern "C" void kernel_launch(void* const* d_in, const int* in_sizes, int n_in,
                              void* d_out, int out_size, void* d_ws, size_t ws_size,
                              hipStream_t stream) {
    const float* img = (const float*)d_in[0];
    _Float16* b0 = (_Float16*)d_ws;
    _Float16* b1 = b0 + TOTAL_ELEMS;
    _Float16* b2 = b1 + TOTAL_ELEMS;
    _Float16* S  = b2 + TOTAL_ELEMS;  // 4 x 28.3 MB workspace

    // Chain A_0=img, A_j=erode(A_{j-1}). Steps j=1..41.
    erode_k<<<NBLK_E, 256, 0, stream>>>(img, b0);                      // b0 = A_1
    // K_0: steps 1,2. P=img(fp32), C=A_1 -> T=A_2 (b1), U=A_3 (b2), S init+upd.
    double_k<true><<<NBLK_F, 256, 0, stream>>>(img, b0, S, b1, b2);
    // K_t (t=1..19): steps 2t+1, 2t+2. P=b1 (A_2t), T in-place to b1 (A_{2t+2});
    // C/U alternate b2/b0.
    for (int tt = 1; tt <= 19; ++tt) {
        _Float16* Cb = (tt & 1) ? b2 : b0;
        _Float16* Ub = (tt & 1) ? b0 : b2;
        double_k<false><<<NBLK_F, 256, 0, stream>>>(b1, Cb, S, b1, Ub);
    }
    // After K_19: b1 = A_40, b0 = A_41. Final step j=41 -> fp32 d_out.
    final_k<<<NBLK_F, 256, 0, stream>>>(b0, b1, S, (float*)d_out);
}

// Round 8
// 1480.773 us; speedup vs baseline: 1.1577x; 1.1577x over previous
//
#include <hip/hip_runtime.h>
#include <float.h>

// Volume geometry: (B=2, C=1, D=192, H=192, W=192) fp32 in/out.
// Erosion chain + skel stored fp16: min/max are SELECTIONS (one initial
// rounding, no accumulation); skel arithmetic fp32 in-register, fp16 stored.
// R7 post-mortem: two-step temporal fusion regressed (VALU 65%, 87us) -> this
// reverts to the R6 single-step z-march and widens lanes to half8 (16B/lane).
#define Dn 192
#define Hn 192
#define Wn 192
#define PLANE (Hn * Wn)            // 36864 elems
#define W4n 48                     // float4 groups per row (erode_k)
#define W8n 24                     // half8 groups per row (fused)
#define TOTAL_ELEMS 14155776       // 2*192^3
#define TOTAL_T4 (TOTAL_ELEMS / 4) // float4 groups
#define TOTAL_T8 (TOTAL_ELEMS / 8) // half8 groups = 1769472
#define ZPT 8                      // z per thread (fused)
#define ZC (Dn / ZPT)              // 24 z-chunks
#define NBLK_F (TOTAL_T8 / ZPT / 256)  // 864 blocks (fused)
#define NBLK_E (TOTAL_T4 / 256)        // 13824 blocks (standalone erode)

typedef _Float16 half8 __attribute__((ext_vector_type(8)));

// ---- fp32 4-wide helpers (erode_k only) ----
__device__ __forceinline__ float4 f4min(float4 a, float4 b) {
    return make_float4(fminf(a.x, b.x), fminf(a.y, b.y), fminf(a.z, b.z), fminf(a.w, b.w));
}
__device__ __forceinline__ float4 hmin3n(float4 v, float nl, float nr, int w4) {
    float l = (w4 > 0)  ? nl : v.x;
    float r = (w4 < 47) ? nr : v.w;
    return make_float4(fminf(fminf(l, v.x), v.y), fminf(fminf(v.x, v.y), v.z),
                       fminf(fminf(v.y, v.z), v.w), fminf(fminf(v.z, v.w), r));
}

// ---- fp16 packed helpers ----
__device__ __forceinline__ _Float16 hmin(_Float16 a, _Float16 b) { return a < b ? a : b; }
__device__ __forceinline__ _Float16 hmax(_Float16 a, _Float16 b) { return a > b ? a : b; }
__device__ __forceinline__ half8 h8min(half8 a, half8 b) {
    half8 o;
#pragma unroll
    for (int i = 0; i < 8; ++i) o[i] = a[i] < b[i] ? a[i] : b[i];
    return o;
}
__device__ __forceinline__ half8 h8max(half8 a, half8 b) {
    half8 o;
#pragma unroll
    for (int i = 0; i < 8; ++i) o[i] = a[i] > b[i] ? a[i] : b[i];
    return o;
}
// shift-by-one with injected boundary scalar (compiler -> v_alignbit chains)
__device__ __forceinline__ half8 shl1(half8 v, _Float16 l) {
    half8 o; o[0] = l;
#pragma unroll
    for (int i = 1; i < 8; ++i) o[i] = v[i - 1];
    return o;
}
__device__ __forceinline__ half8 shr1(half8 v, _Float16 r) {
    half8 o;
#pragma unroll
    for (int i = 0; i < 7; ++i) o[i] = v[i + 1];
    o[7] = r;
    return o;
}
__device__ __forceinline__ _Float16 shfl_up_h(_Float16 v)  { return (_Float16)__shfl_up((float)v, 1); }
__device__ __forceinline__ _Float16 shfl_dn_h(_Float16 v)  { return (_Float16)__shfl_down((float)v, 1); }

// XCD-aware swizzle: contiguous slab per XCD so stencil reuse hits its L2.
template <int CHUNK>
__device__ __forceinline__ int swizzle(int bid) {
    return (bid & 7) * CHUNK + (bid >> 3);
}

// Raw fp16 rows of one plane at (b,y,x8): up/center/down half8 + patch column
// (x-1 for a mid-row wave-start lane, x+8 for a mid-row wave-end lane).
// Missing y-rows padded with center row (neutral for min and max). Kept packed;
// summarize8 consumes one pipeline stage later (load latency covered).
struct Raw { half8 u, c, d; _Float16 pu, pc, pd; };

__device__ __forceinline__ void load_raw(const _Float16* __restrict__ A, int pb,
                                         bool hasU, bool hasD, int w8, int lane,
                                         Raw& r) {
    const _Float16* p = A + pb;
    r.c = *(const half8*)p;
    half8 u = r.c, d = r.c;
    if (hasU) u = *(const half8*)(p - Wn);
    if (hasD) d = *(const half8*)(p + Wn);
    r.u = u; r.d = d;
    r.pu = r.pc = r.pd = (_Float16)0.f;
    int o = (lane == 0) ? -1 : 8;
    if ((lane == 0 && w8 > 0) || (lane == 63 && w8 < 23)) {
        _Float16 pc = p[o];
        _Float16 pu = pc, pd = pc;
        if (hasU) pu = p[o - Wn];
        if (hasD) pd = p[o + Wn];
        r.pc = pc; r.pu = pu; r.pd = pd;
    }
}

// Plane summaries (all packed fp16 — exact selections):
//   mx = 3x3 (x,y)-box max; st = erode star's in-plane min; cr = center row.
__device__ __forceinline__ void summarize8(const Raw& r, int w8, int lane,
                                           half8& mx, half8& st, half8& cr) {
    half8 mv = h8max(r.c, h8max(r.u, r.d));
    half8 mn = h8min(r.u, r.d);
    _Float16 mvl = shfl_up_h(mv[7]);
    _Float16 mvr = shfl_dn_h(mv[0]);
    _Float16 cl  = shfl_up_h(r.c[7]);
    _Float16 crr = shfl_dn_h(r.c[0]);
    _Float16 pm = hmax(r.pc, hmax(r.pu, r.pd));
    if (lane == 0 && w8 > 0)   { mvl = pm; cl = r.pc; }
    if (lane == 63 && w8 < 23) { mvr = pm; crr = r.pc; }
    if (w8 == 0)  { mvl = mv[0]; cl = r.c[0]; }   // neutral x-pad
    if (w8 == 23) { mvr = mv[7]; crr = r.c[7]; }
    mx = h8max(h8max(shl1(mv, mvl), shr1(mv, mvr)), mv);
    st = h8min(h8min(h8min(shl1(r.c, cl), shr1(r.c, crr)), r.c), mn);
    cr = r.c;
}

// Standalone erode: A_1 = erode(img). fp32 in, fp16 out. 7-star min.
__global__ __launch_bounds__(256) void erode_k(const float* __restrict__ in,
                                               _Float16* __restrict__ out) {
    int t = swizzle<NBLK_E / 8>(blockIdx.x) * 256 + threadIdx.x;
    int lane = threadIdx.x & 63;
    int w4 = t % W4n;
    int r  = t / W4n;
    int y  = r % Hn;
    int r2 = r / Hn;
    int z  = r2 % Dn;
    int b  = r2 / Dn;
    int base = ((b * Dn + z) * Hn + y) * Wn + w4 * 4;

    const float* p = in + base;
    float4 c = *(const float4*)p;
    float nl = __shfl_up(c.w, 1), nr = __shfl_down(c.x, 1);
    if (lane == 0 && w4 > 0)   nl = p[-1];
    if (lane == 63 && w4 < 47) nr = p[4];
    float4 acc = hmin3n(c, nl, nr, w4);
    if (z > 0)      acc = f4min(acc, *(const float4*)(p - PLANE));
    if (z < Dn - 1) acc = f4min(acc, *(const float4*)(p + PLANE));
    if (y > 0)      acc = f4min(acc, *(const float4*)(p - Wn));
    if (y < Hn - 1) acc = f4min(acc, *(const float4*)(p + Wn));
    _Float16* q = out + base;
#pragma unroll
    for (int i = 0; i < 4; ++i) { }
    half8 dummy;  // (unused; keep types simple)
    // store 4 fp16 (8B)
    _Float16 o0 = (_Float16)acc.x, o1 = (_Float16)acc.y,
             o2 = (_Float16)acc.z, o3 = (_Float16)acc.w;
    q[0] = o0; q[1] = o1; q[2] = o2; q[3] = o3;
}

// Fused step j, software-pipelined z-march, half8 lanes (see R4-R6).
// D(z)=max(mx[z-1..z+1]); Emin(z)=min(st[z], cr[z-1], cr[z+1]).
// FIRST: E = fp32 img, skel starts at 0.  LAST: write fp32 to d_out, no Anext.
// E/Anext may alias; Sin/Sout alias in mid steps (same-thread same-base only).
template <bool FIRST, bool LAST>
__global__ __launch_bounds__(256, 3) void fused_k(const _Float16* __restrict__ A,
                                                  const void* E_,
                                                  const _Float16* Sin,
                                                  void* Sout_,
                                                  _Float16* Anext) {
    const float* Ef    = (const float*)E_;
    const _Float16* Eh = (const _Float16*)E_;
    _Float16* Sh = (_Float16*)Sout_;
    float* Sf    = (float*)Sout_;
    int t = swizzle<NBLK_F / 8>(blockIdx.x) * 256 + threadIdx.x;
    int lane = threadIdx.x & 63;
    int w8 = t % W8n;
    int r  = t / W8n;
    int y  = r % Hn;
    int r2 = r / Hn;
    int zc = r2 % ZC;   // wave-uniform: 24*192 = 4608 groups per (b,zc), 64|4608
    int b  = r2 / ZC;
    int z0 = zc * ZPT;
    bool hasU = (y > 0), hasD = (y < Hn - 1);
    int base0 = ((b * Dn + z0) * Hn + y) * Wn + w8 * 8;

    half8 mx0, mx1, mx2, st1, st2, cr0, cr1, cr2;
    Raw bufA, bufB, rP;

    // Prologue: issue ALL leading loads before any dependent compute.
    if (z0 > 0) load_raw(A, base0 - PLANE, hasU, hasD, w8, lane, rP);
    load_raw(A, base0,         hasU, hasD, w8, lane, bufB);  // plane z0
    load_raw(A, base0 + PLANE, hasU, hasD, w8, lane, bufA);  // plane z0+1
    float ePf[8]; half8 ePh, sPh;
    if (FIRST) {
        float4 a0 = *(const float4*)(Ef + base0);
        float4 a1 = *(const float4*)(Ef + base0 + 4);
        ePf[0]=a0.x; ePf[1]=a0.y; ePf[2]=a0.z; ePf[3]=a0.w;
        ePf[4]=a1.x; ePf[5]=a1.y; ePf[6]=a1.z; ePf[7]=a1.w;
    } else {
        ePh = *(const half8*)(Eh + base0);
        sPh = *(const half8*)(Sin + base0);
    }

    half8 stP;
    if (z0 > 0) summarize8(rP, w8, lane, mx0, stP, cr0);
    summarize8(bufB, w8, lane, mx1, st1, cr1);
    if (z0 == 0) { mx0 = mx1; cr0 = cr1; }   // neutral z-pad

    int pb = base0;
#pragma unroll
    for (int i = 0; i < ZPT; ++i) {
        Raw& cur = (i & 1) ? bufB : bufA;   // holds plane z+1
        Raw& nxt = (i & 1) ? bufA : bufB;   // receives plane z+2
        // 1) issue next plane's raw loads (consumed at iter i+1)
        if (i + 1 < ZPT && z0 + i + 2 < Dn)
            load_raw(A, pb + 2 * PLANE, hasU, hasD, w8, lane, nxt);
        // 2) issue next E/skel prefetch (consumed next iter)
        float eNf[8]; half8 eNh = ePh, sNh = sPh;
        if (FIRST) {
#pragma unroll
            for (int k = 0; k < 8; ++k) eNf[k] = ePf[k];
        }
        if (i + 1 < ZPT) {
            if (FIRST) {
                float4 a0 = *(const float4*)(Ef + pb + PLANE);
                float4 a1 = *(const float4*)(Ef + pb + PLANE + 4);
                eNf[0]=a0.x; eNf[1]=a0.y; eNf[2]=a0.z; eNf[3]=a0.w;
                eNf[4]=a1.x; eNf[5]=a1.y; eNf[6]=a1.z; eNf[7]=a1.w;
            } else {
                eNh = *(const half8*)(Eh + pb + PLANE);
                sNh = *(const half8*)(Sin + pb + PLANE);
            }
        }
        // 3) summarize plane z+1 (its loads were issued one iteration ago)
        if (z0 + i + 1 < Dn) summarize8(cur, w8, lane, mx2, st2, cr2);
        else { mx2 = mx1; st2 = st1; cr2 = cr1; }  // neutral z-pad
        // 4) combine & store for z (skel math fp32)
        half8 dil = h8max(mx1, h8max(mx0, mx2));
        if (LAST) {
            float o[8];
#pragma unroll
            for (int k = 0; k < 8; ++k) {
                float e = (float)ePh[k];
                float d = fmaxf(e - (float)dil[k], 0.f);
                float s = (float)sPh[k];
                o[k] = s + fmaxf(d - s * d, 0.f);
            }
            *(float4*)(Sf + pb)     = make_float4(o[0], o[1], o[2], o[3]);
            *(float4*)(Sf + pb + 4) = make_float4(o[4], o[5], o[6], o[7]);
        } else {
            half8 so;
#pragma unroll
            for (int k = 0; k < 8; ++k) {
                float e = FIRST ? ePf[k] : (float)ePh[k];
                float d = fmaxf(e - (float)dil[k], 0.f);
                float s;
                if (FIRST) s = d;      // skel starts at 0
                else {
                    s = (float)sPh[k];
                    s += fmaxf(d - s * d, 0.f);
                }
                so[k] = (_Float16)s;
            }
            *(half8*)(Sh + pb) = so;
            half8 er = h8min(st1, h8min(cr0, cr2));
            *(half8*)(Anext + pb) = er;
        }
        // 5) rotate pipeline state
        mx0 = mx1; cr0 = cr1;
        mx1 = mx2; st1 = st2; cr1 = cr2;
        if (FIRST) {
#pragma unroll
            for (int k = 0; k < 8; ++k) ePf[k] = eNf[k];
        }
        ePh = eNh; sPh = sNh;
        pb += PLANE;
    }
}

extern "C" void kernel_launch(void* const* d_in, const int* in_sizes, int n_in,
                              void* d_out, int out_size, void* d_ws, size_t ws_size,
                              hipStream_t stream) {
    const float* img = (const float*)d_in[0];
    _Float16* B0 = (_Float16*)d_ws;
    _Float16* B1 = B0 + TOTAL_ELEMS;
    _Float16* S  = B1 + TOTAL_ELEMS;  // 3 x 28.3 MB workspace

    // Erosion chain A_0=img, A_j=erode(A_{j-1}) stored fp16.
    // Step j (1..41): delta = relu(A_{j-1} - dilate(A_j)); skel-accumulate
    // (fp16 in ws; final step writes fp32 to d_out).
    erode_k<<<NBLK_E, 256, 0, stream>>>(img, B0);                            // B0 = A_1
    fused_k<true, false><<<NBLK_F, 256, 0, stream>>>(B0, img, S, S, B1);     // j=1

    _Float16* a = B1;  // A_j
    _Float16* e = B0;  // A_{j-1}; overwritten in-place with A_{j+1}
    for (int j = 2; j <= 40; ++j) {
        fused_k<false, false><<<NBLK_F, 256, 0, stream>>>(a, e, S, S, e);
        _Float16* tmp = a; a = e; e = tmp;
    }
    // j=41: read fp16 skel, write fp32 result to d_out; no erode output.
    fused_k<false, true><<<NBLK_F, 256, 0, stream>>>(a, e, S, d_out, nullptr);
}

// Round 9
// 1244.982 us; speedup vs baseline: 1.3770x; 1.1894x over previous
//
#include <hip/hip_runtime.h>
#include <float.h>

// Volume geometry: (B=2, C=1, D=192, H=192, W=192) fp32 in/out.
// Erosion chain + skel stored fp16: min/max are SELECTIONS (one initial
// rounding, no accumulation); skel arithmetic fp32 in-register, fp16 stored.
// R7 (2-step register fusion): FAILED, VALU 65%. R8 (half8 lanes): FAILED,
// halved wave count -> latency-bound BW halved. This round: R6 half4 z-march
// + 128-thread blocks (2x blocks) + depth-2 prefetch (2x bytes in flight).
#define Dn 192
#define Hn 192
#define Wn 192
#define PLANE (Hn * Wn)            // 36864 elems
#define W4n 48                     // half4 groups per row
#define TOTAL_ELEMS 14155776       // 2*192^3
#define TOTAL_T4 (TOTAL_ELEMS / 4) // 3538944 groups
#define ZPT 8                      // z per thread (fused)
#define ZC (Dn / ZPT)              // 24 z-chunks
#define BLK_F 128                  // fused block size (2 waves)
#define NBLK_F (TOTAL_T4 / ZPT / BLK_F)  // 3456 blocks
#define NBLK_E (TOTAL_T4 / 256)          // 13824 blocks (standalone erode)

typedef _Float16 half4 __attribute__((ext_vector_type(4)));

// ---- fp32 helpers ----
__device__ __forceinline__ float4 f4min(float4 a, float4 b) {
    return make_float4(fminf(a.x, b.x), fminf(a.y, b.y), fminf(a.z, b.z), fminf(a.w, b.w));
}
__device__ __forceinline__ float4 f4max(float4 a, float4 b) {
    return make_float4(fmaxf(a.x, b.x), fmaxf(a.y, b.y), fmaxf(a.z, b.z), fmaxf(a.w, b.w));
}
__device__ __forceinline__ float4 h4tof4(half4 h) {
    return make_float4((float)h.x, (float)h.y, (float)h.z, (float)h.w);
}
__device__ __forceinline__ half4 f4toh4(float4 f) {
    half4 h; h.x = (_Float16)f.x; h.y = (_Float16)f.y;
    h.z = (_Float16)f.z; h.w = (_Float16)f.w; return h;
}
__device__ __forceinline__ float4 hmax3n(float4 v, float nl, float nr, int w4) {
    float l = (w4 > 0)  ? nl : v.x;     // neutral x-pad
    float r = (w4 < 47) ? nr : v.w;
    return make_float4(fmaxf(fmaxf(l, v.x), v.y), fmaxf(fmaxf(v.x, v.y), v.z),
                       fmaxf(fmaxf(v.y, v.z), v.w), fmaxf(fmaxf(v.z, v.w), r));
}
__device__ __forceinline__ float4 hmin3n(float4 v, float nl, float nr, int w4) {
    float l = (w4 > 0)  ? nl : v.x;
    float r = (w4 < 47) ? nr : v.w;
    return make_float4(fminf(fminf(l, v.x), v.y), fminf(fminf(v.x, v.y), v.z),
                       fminf(fminf(v.y, v.z), v.w), fminf(fminf(v.z, v.w), r));
}

// XCD-aware swizzle: contiguous slab per XCD so stencil reuse hits its L2.
template <int CHUNK>
__device__ __forceinline__ int swizzle(int bid) {
    return (bid & 7) * CHUNK + (bid >> 3);
}

// Raw fp16 rows of one plane at (b,y,x4): up/center/down half4 + patch column
// (x-1 for mid-row wave-start lane, x+4 for mid-row wave-end lane). Missing
// y-rows padded with center row (neutral for min and max). Kept packed; fp32
// conversion deferred to summarize() >=2 pipeline stages later.
struct Raw { half4 u, c, d; _Float16 pu, pc, pd; };

__device__ __forceinline__ void load_raw(const _Float16* __restrict__ A, int pb,
                                         bool hasU, bool hasD, int w4, int lane,
                                         Raw& r) {
    const _Float16* p = A + pb;
    r.c = *(const half4*)p;
    half4 u = r.c, d = r.c;
    if (hasU) u = *(const half4*)(p - Wn);
    if (hasD) d = *(const half4*)(p + Wn);
    r.u = u; r.d = d;
    r.pu = r.pc = r.pd = (_Float16)0.f;
    int o = (lane == 0) ? -1 : 4;
    if ((lane == 0 && w4 > 0) || (lane == 63 && w4 < 47)) {
        _Float16 pc = p[o];
        _Float16 pu = pc, pd = pc;
        if (hasU) pu = p[o - Wn];
        if (hasD) pd = p[o + Wn];
        r.pc = pc; r.pu = pu; r.pd = pd;
    }
}

// Plane summaries: mx = 3x3 (x,y)-box max; st = erode star's in-plane min;
// cr = center row (fp32).
__device__ __forceinline__ void summarize(const Raw& r, int w4, int lane,
                                          float4& mx, float4& st, float4& cr) {
    float4 c = h4tof4(r.c), u = h4tof4(r.u), d = h4tof4(r.d);
    float4 mv = f4max(c, f4max(u, d));
    float mvl = __shfl_up(mv.w, 1);
    float mvr = __shfl_down(mv.x, 1);
    float cl  = __shfl_up(c.w, 1);
    float crr = __shfl_down(c.x, 1);
    float puf = (float)r.pu, pcf = (float)r.pc, pdf = (float)r.pd;
    float pm = fmaxf(pcf, fmaxf(puf, pdf));
    if (lane == 0 && w4 > 0)   { mvl = pm; cl = pcf; }
    if (lane == 63 && w4 < 47) { mvr = pm; crr = pcf; }
    mx = hmax3n(mv, mvl, mvr, w4);
    st = f4min(hmin3n(c, cl, crr, w4), f4min(u, d));
    cr = c;
}

__device__ __forceinline__ float4 skel_upd(float4 s, float4 d) {
    s.x += fmaxf(d.x - s.x * d.x, 0.f);
    s.y += fmaxf(d.y - s.y * d.y, 0.f);
    s.z += fmaxf(d.z - s.z * d.z, 0.f);
    s.w += fmaxf(d.w - s.w * d.w, 0.f);
    return s;
}

// Standalone erode: A_1 = erode(img). fp32 in, fp16 out. 7-star min.
__global__ __launch_bounds__(256) void erode_k(const float* __restrict__ in,
                                               _Float16* __restrict__ out) {
    int t = swizzle<NBLK_E / 8>(blockIdx.x) * 256 + threadIdx.x;
    int lane = threadIdx.x & 63;
    int w4 = t % W4n;
    int r  = t / W4n;
    int y  = r % Hn;
    int r2 = r / Hn;
    int z  = r2 % Dn;
    int b  = r2 / Dn;
    int base = ((b * Dn + z) * Hn + y) * Wn + w4 * 4;

    const float* p = in + base;
    float4 c = *(const float4*)p;
    float nl = __shfl_up(c.w, 1), nr = __shfl_down(c.x, 1);
    if (lane == 0 && w4 > 0)   nl = p[-1];
    if (lane == 63 && w4 < 47) nr = p[4];
    float4 acc = hmin3n(c, nl, nr, w4);
    if (z > 0)      acc = f4min(acc, *(const float4*)(p - PLANE));
    if (z < Dn - 1) acc = f4min(acc, *(const float4*)(p + PLANE));
    if (y > 0)      acc = f4min(acc, *(const float4*)(p - Wn));
    if (y < Hn - 1) acc = f4min(acc, *(const float4*)(p + Wn));
    *(half4*)(out + base) = f4toh4(acc);
}

// Fused step j, z-march with DEPTH-2 software pipeline:
//   A planes in a ring of 3: plane z+3 issued at iter i, summarized at i+2.
//   E/S prefetched two planes ahead.
// D(z)=max(mx[z-1..z+1]); Emin(z)=min(st[z], cr[z-1], cr[z+1]).
// FIRST: E = fp32 img, skel starts 0. LAST: fp32 out to d_out, no Anext.
// E/Anext may alias; Sin/Sout alias in mid steps (same-thread same-base only).
template <bool FIRST, bool LAST>
__global__ __launch_bounds__(BLK_F, 4) void fused_k(const _Float16* __restrict__ A,
                                                    const void* E_,
                                                    const _Float16* Sin,
                                                    void* Sout_,
                                                    _Float16* Anext) {
    const float* Ef    = (const float*)E_;
    const _Float16* Eh = (const _Float16*)E_;
    _Float16* Sh = (_Float16*)Sout_;
    float* Sf    = (float*)Sout_;
    int t = swizzle<NBLK_F / 8>(blockIdx.x) * BLK_F + threadIdx.x;
    int lane = threadIdx.x & 63;
    int w4 = t % W4n;
    int r  = t / W4n;
    int y  = r % Hn;
    int r2 = r / Hn;
    int zc = r2 % ZC;   // wave/block-uniform: 9216 groups per (b,zc), 128|9216
    int b  = r2 / ZC;
    int z0 = zc * ZPT;
    bool hasU = (y > 0), hasD = (y < Hn - 1);
    int base0 = ((b * Dn + z0) * Hn + y) * Wn + w4 * 4;

    float4 mx0, mx1, mx2, st1, st2, cr0, cr1, cr2, stP;
    Raw R[3], rP;

    // Prologue: issue ALL leading loads (planes z0-1..z0+2, E/S at z0,z0+1)
    // before any dependent compute.
    if (z0 > 0) load_raw(A, base0 - PLANE, hasU, hasD, w4, lane, rP);
    load_raw(A, base0,             hasU, hasD, w4, lane, R[0]);
    load_raw(A, base0 + PLANE,     hasU, hasD, w4, lane, R[1]);
    load_raw(A, base0 + 2 * PLANE, hasU, hasD, w4, lane, R[2]);  // z0+2<=186<192
    float4 eP_f, eN_f; half4 eP_h, eN_h, sP_h, sN_h;
    if (FIRST) {
        eP_f = *(const float4*)(Ef + base0);
        eN_f = *(const float4*)(Ef + base0 + PLANE);
    } else {
        eP_h = *(const half4*)(Eh + base0);
        eN_h = *(const half4*)(Eh + base0 + PLANE);
        sP_h = *(const half4*)(Sin + base0);
        sN_h = *(const half4*)(Sin + base0 + PLANE);
    }

    if (z0 > 0) summarize(rP, w4, lane, mx0, stP, cr0);
    summarize(R[0], w4, lane, mx1, st1, cr1);
    if (z0 == 0) { mx0 = mx1; cr0 = cr1; }   // neutral z-pad

    int pb = base0;
#pragma unroll
    for (int i = 0; i < ZPT; ++i) {
        // 1) issue plane z0+i+3 into ring slot i%3 (summarized at iter i+2)
        if (i + 3 <= ZPT && z0 + i + 3 < Dn)
            load_raw(A, pb + 3 * PLANE, hasU, hasD, w4, lane, R[i % 3]);
        // 2) issue E/S for z0+i+2 (consumed at iter i+2)
        float4 eN2_f = eN_f; half4 eN2_h = eN_h, sN2_h = sN_h;
        if (i + 2 < ZPT) {
            if (FIRST) eN2_f = *(const float4*)(Ef + pb + 2 * PLANE);
            else {
                eN2_h = *(const half4*)(Eh + pb + 2 * PLANE);
                sN2_h = *(const half4*)(Sin + pb + 2 * PLANE);
            }
        }
        // 3) summarize plane z+1 (its loads were issued >=2 iterations ago)
        if (z0 + i + 1 < Dn) summarize(R[(i + 1) % 3], w4, lane, mx2, st2, cr2);
        else { mx2 = mx1; st2 = st1; cr2 = cr1; }  // neutral z-pad
        // 4) combine & store for z (skel math fp32)
        float4 dil = f4max(mx1, f4max(mx0, mx2));
        float4 e = FIRST ? eP_f : h4tof4(eP_h);
        float4 delta = make_float4(fmaxf(e.x - dil.x, 0.f), fmaxf(e.y - dil.y, 0.f),
                                   fmaxf(e.z - dil.z, 0.f), fmaxf(e.w - dil.w, 0.f));
        float4 s;
        if (FIRST) s = delta;                       // skel starts at 0
        else       s = skel_upd(h4tof4(sP_h), delta);
        if (LAST) {
            *(float4*)(Sf + pb) = s;                // final: fp32 to d_out
        } else {
            *(half4*)(Sh + pb) = f4toh4(s);
            float4 er = f4min(st1, f4min(cr0, cr2));
            *(half4*)(Anext + pb) = f4toh4(er);
        }
        // 5) rotate pipeline state
        mx0 = mx1; cr0 = cr1;
        mx1 = mx2; st1 = st2; cr1 = cr2;
        eP_f = eN_f; eN_f = eN2_f;
        eP_h = eN_h; eN_h = eN2_h;
        sP_h = sN_h; sN_h = sN2_h;
        pb += PLANE;
    }
}

extern "C" void kernel_launch(void* const* d_in, const int* in_sizes, int n_in,
                              void* d_out, int out_size, void* d_ws, size_t ws_size,
                              hipStream_t stream) {
    const float* img = (const float*)d_in[0];
    _Float16* B0 = (_Float16*)d_ws;
    _Float16* B1 = B0 + TOTAL_ELEMS;
    _Float16* S  = B1 + TOTAL_ELEMS;  // 3 x 28.3 MB workspace

    // Erosion chain A_0=img, A_j=erode(A_{j-1}) stored fp16.
    // Step j (1..41): delta = relu(A_{j-1} - dilate(A_j)); skel-accumulate
    // (fp16 in ws; final step writes fp32 to d_out).
    erode_k<<<NBLK_E, 256, 0, stream>>>(img, B0);                            // B0 = A_1
    fused_k<true, false><<<NBLK_F, BLK_F, 0, stream>>>(B0, img, S, S, B1);   // j=1

    _Float16* a = B1;  // A_j
    _Float16* e = B0;  // A_{j-1}; overwritten in-place with A_{j+1}
    for (int j = 2; j <= 40; ++j) {
        fused_k<false, false><<<NBLK_F, BLK_F, 0, stream>>>(a, e, S, S, e);
        _Float16* tmp = a; a = e; e = tmp;
    }
    // j=41: read fp16 skel, write fp32 result to d_out; no erode output.
    fused_k<false, true><<<NBLK_F, BLK_F, 0, stream>>>(a, e, S, d_out, nullptr);
}